// Round 7
// baseline (463.397 us; speedup 1.0000x reference)
//
#include <hip/hip_runtime.h>
#include <stdint.h>

#define NN 8192
#define FF 256
#define HH 64

typedef __attribute__((ext_vector_type(8))) short bf16x8;
typedef __attribute__((ext_vector_type(4))) float f32x4;

__device__ __forceinline__ uint16_t f2bf(float f) {
  union { float f; uint32_t i; } c; c.f = f;
  uint32_t r = c.i + 0x7FFFu + ((c.i >> 16) & 1u);
  return (uint16_t)(r >> 16);
}

// async global->LDS DMA, 16B per lane (dest = wave-uniform base + lane*16)
__device__ __forceinline__ void gload_lds16(const void* g, void* l) {
  __builtin_amdgcn_global_load_lds(
      (const __attribute__((address_space(1))) unsigned int*)g,
      (__attribute__((address_space(3))) unsigned int*)l, 16, 0, 0);
}

// ---------------------------------------------------------------------------
// K1: verified r5..r11 GEMM core + verified LDS-transpose tail (passed
// R1/R2/R6). Unchanged. grid = 256 x 32 rows.
// ---------------------------------------------------------------------------
__global__ __launch_bounds__(256) void k1_h(
    const float* __restrict__ x, const float* __restrict__ Wt,
    const float* __restrict__ bt, uint16_t* __restrict__ hT) {
  __shared__ float wtT[256 * 65];
  __shared__ float sbt[64];
  __shared__ uint16_t s_tr[64][34];
  const int t = threadIdx.x;
  const int lane = t & 63;
  const int w = t >> 6;

  for (int i = 0; i < 64; ++i)
    wtT[t * 65 + i] = Wt[(size_t)i * FF + t];
  if (t < 64) sbt[t] = bt[t];
  __syncthreads();

  const int n0 = blockIdx.x * 32;
  const int r0 = n0 + w * 8;
  const float binit = sbt[lane];
  float acc[8];
#pragma unroll
  for (int r = 0; r < 8; ++r) acc[r] = binit;

  for (int f4 = 0; f4 < FF; f4 += 4) {
    float4 xs[8];
#pragma unroll
    for (int r = 0; r < 8; ++r)
      xs[r] = *(const float4*)(x + (size_t)(r0 + r) * FF + f4);
    const float wt0 = wtT[(f4 + 0) * 65 + lane];
    const float wt1 = wtT[(f4 + 1) * 65 + lane];
    const float wt2 = wtT[(f4 + 2) * 65 + lane];
    const float wt3 = wtT[(f4 + 3) * 65 + lane];
#pragma unroll
    for (int r = 0; r < 8; ++r)
      acc[r] += xs[r].x * wt0 + xs[r].y * wt1 + xs[r].z * wt2 + xs[r].w * wt3;
  }

#pragma unroll
  for (int r = 0; r < 8; ++r)
    s_tr[lane][w * 8 + r] = f2bf(acc[r]);
  __syncthreads();
#pragma unroll
  for (int i = 0; i < 4; ++i) {
    int idx = i * 256 + t;
    int c = idx >> 4;
    int d = idx & 15;
    uint32_t v = (uint32_t)s_tr[c][2 * d] | ((uint32_t)s_tr[c][2 * d + 1] << 16);
    *(uint32_t*)(hT + (size_t)c * NN + n0 + 2 * d) = v;
  }
}

// ---------------------------------------------------------------------------
// K2 v3: R6's verified skeleton (split-K 2, grid 1024, block-wide
// __syncthreads ordering ONLY, verbatim MFMA/acc/epilogue maps) with the
// staging mechanism replaced by async global_load_lds DMA:
//  * 256-col int32 tiles, double-buffered (2 x 16 KB); one DMA issue stages
//    one row (1 KB, 64 lanes x 16B), wave w stages rows w*4..w*4+3.
//  * next tile's DMA issued BEFORE compute; the single __syncthreads per
//    tile drains it AFTER compute has hidden the latency. 48 KB/CU in
//    flight (vs ~3 KB with register staging) lifts the Little's-law cap.
//  * rule-21 swizzle: linear DMA dest + inverse-swizzled GLOBAL source
//    (lane^(s&7)) + XOR-swizzled b128 reads; int->bf16 packed-mult convert
//    (R2-verified trick) moves to the read path.
// ---------------------------------------------------------------------------
__global__ __launch_bounds__(256) void k2_attn(
    const int* __restrict__ adj, const uint16_t* __restrict__ hT,
    float* __restrict__ nb_part, float* __restrict__ deg_part) {
  __shared__ __align__(16) unsigned char af[2][16384];  // raw int32 tiles
  __shared__ float s_part[4][16][64];                   // 16 KB
  __shared__ float s_degw[4][16];

  const int t    = threadIdx.x;
  const int w    = t >> 6;
  const int lane = t & 63;
  const int m    = lane & 15;
  const int q    = lane >> 4;
  const int g    = blockIdx.x >> 1;
  const int half = blockIdx.x & 1;
  const int row0 = g * 16;
  const uint32_t rsw = (uint32_t)((m & 7) << 4);

  bf16x8 vone;
#pragma unroll
  for (int j = 0; j < 8; ++j) vone[j] = (short)0x3F80;

  f32x4 acc0 = 0, acc1 = 0, acc2 = 0, acc3 = 0, accd = 0;
  const uint16_t* __restrict__ hrow = hT + (size_t)m * NN;
  const int base = half * (NN / 2);

  // hoisted, tile-invariant LDS read offsets (logical colbyte ^ row-swizzle)
  const int kl = w * 64;                            // wave's cols in tile
  const uint32_t cbA  = (uint32_t)((kl + q * 8) * 4);  // bit4 == 0
  const uint32_t o_a0 = (uint32_t)(m * 1024) + ( cbA         ^ rsw);
  const uint32_t o_a1 = (uint32_t)(m * 1024) + ((cbA +  16u) ^ rsw);
  const uint32_t o_b0 = (uint32_t)(m * 1024) + ((cbA + 128u) ^ rsw);
  const uint32_t o_b1 = (uint32_t)(m * 1024) + ((cbA + 144u) ^ rsw);

  // DMA staging: sub-issue j stages row s = w*4+j of the tile; lane sources
  // global ints (lane ^ (s&7))*4 (inverse swizzle -> XOR layout in LDS).
#define STAGE_DMA(BUF, C0)                                                   \
  _Pragma("unroll") for (int j = 0; j < 4; ++j) {                            \
    const int s_ = w * 4 + j;                                                \
    gload_lds16(adj + (size_t)(row0 + s_) * NN + (C0) +                      \
                    ((lane ^ (s_ & 7)) * 4),                                 \
                &af[BUF][s_ * 1024]);                                        \
  }

  // prologue: stage tile 0
  STAGE_DMA(0, base)
  __syncthreads();

  int c0 = base;
  for (int tile = 0; tile < 16; ++tile) {
    const int buf = tile & 1;
    if (tile < 15) STAGE_DMA(buf ^ 1, c0 + 256)   // async, flies over compute

    // ---- compute from af[buf]: convert + verbatim R2/R6 MFMA body ----
    {
      const unsigned char* cb_ = af[buf];
      int4 ra0 = *(const int4*)(cb_ + o_a0);
      int4 ra1 = *(const int4*)(cb_ + o_a1);
      int4 rb0 = *(const int4*)(cb_ + o_b0);
      int4 rb1 = *(const int4*)(cb_ + o_b1);
      union U { bf16x8 v; uint32_t u[4]; } afA, afB;
      afA.u[0] = ((uint32_t)ra0.x | ((uint32_t)ra0.y << 16)) * 0x3F80u;
      afA.u[1] = ((uint32_t)ra0.z | ((uint32_t)ra0.w << 16)) * 0x3F80u;
      afA.u[2] = ((uint32_t)ra1.x | ((uint32_t)ra1.y << 16)) * 0x3F80u;
      afA.u[3] = ((uint32_t)ra1.z | ((uint32_t)ra1.w << 16)) * 0x3F80u;
      afB.u[0] = ((uint32_t)rb0.x | ((uint32_t)rb0.y << 16)) * 0x3F80u;
      afB.u[1] = ((uint32_t)rb0.z | ((uint32_t)rb0.w << 16)) * 0x3F80u;
      afB.u[2] = ((uint32_t)rb1.x | ((uint32_t)rb1.y << 16)) * 0x3F80u;
      afB.u[3] = ((uint32_t)rb1.z | ((uint32_t)rb1.w << 16)) * 0x3F80u;

      const int k0 = c0 + kl + q * 8;
      const int k1 = k0 + 32;
      bf16x8 b0 = *(const bf16x8*)(hrow + k0);
      bf16x8 b1 = *(const bf16x8*)(hrow + 16 * NN + k0);
      bf16x8 b2 = *(const bf16x8*)(hrow + 32 * NN + k0);
      bf16x8 b3 = *(const bf16x8*)(hrow + 48 * NN + k0);
      bf16x8 d0 = *(const bf16x8*)(hrow + k1);
      bf16x8 d1 = *(const bf16x8*)(hrow + 16 * NN + k1);
      bf16x8 d2 = *(const bf16x8*)(hrow + 32 * NN + k1);
      bf16x8 d3 = *(const bf16x8*)(hrow + 48 * NN + k1);
      acc0 = __builtin_amdgcn_mfma_f32_16x16x32_bf16(afA.v, b0, acc0, 0, 0, 0);
      acc1 = __builtin_amdgcn_mfma_f32_16x16x32_bf16(afA.v, b1, acc1, 0, 0, 0);
      acc2 = __builtin_amdgcn_mfma_f32_16x16x32_bf16(afA.v, b2, acc2, 0, 0, 0);
      acc3 = __builtin_amdgcn_mfma_f32_16x16x32_bf16(afA.v, b3, acc3, 0, 0, 0);
      accd = __builtin_amdgcn_mfma_f32_16x16x32_bf16(afA.v, vone, accd, 0, 0, 0);
      acc0 = __builtin_amdgcn_mfma_f32_16x16x32_bf16(afB.v, d0, acc0, 0, 0, 0);
      acc1 = __builtin_amdgcn_mfma_f32_16x16x32_bf16(afB.v, d1, acc1, 0, 0, 0);
      acc2 = __builtin_amdgcn_mfma_f32_16x16x32_bf16(afB.v, d2, acc2, 0, 0, 0);
      acc3 = __builtin_amdgcn_mfma_f32_16x16x32_bf16(afB.v, d3, acc3, 0, 0, 0);
      accd = __builtin_amdgcn_mfma_f32_16x16x32_bf16(afB.v, vone, accd, 0, 0, 0);
    }
    __syncthreads();   // drains next-tile DMA (post-compute) + WAR/RAW order
    c0 += 256;
  }
#undef STAGE_DMA

  // ---- acc -> s_part (R2/R6 verbatim map) + deg-via-MFMA (verbatim) ----
#pragma unroll
  for (int rg = 0; rg < 4; ++rg) {
    s_part[w][q * 4 + rg][ 0 + m] = acc0[rg];
    s_part[w][q * 4 + rg][16 + m] = acc1[rg];
    s_part[w][q * 4 + rg][32 + m] = acc2[rg];
    s_part[w][q * 4 + rg][48 + m] = acc3[rg];
  }
  if (m == 0) {
#pragma unroll
    for (int rg = 0; rg < 4; ++rg) s_degw[w][q * 4 + rg] = accd[rg];
  }
  __syncthreads();

  // ---- cross-wave reduce -> this half's disjoint partial buffers ----
  float* __restrict__ dst = nb_part + ((size_t)half * NN + row0) * HH;
  for (int idx = t; idx < 16 * 64; idx += 256) {
    int r = idx >> 6, c = idx & 63;
    float s = s_part[0][r][c] + s_part[1][r][c] +
              s_part[2][r][c] + s_part[3][r][c];
    dst[(size_t)r * HH + c] = s;
  }
  if (t < 16) {
    float d = s_degw[0][t] + s_degw[1][t] + s_degw[2][t] + s_degw[3][t];
    deg_part[half * NN + row0 + t] = d;
  }
}

// ---------------------------------------------------------------------------
// K3: epilogue, verified maps (passed R6). Unchanged.
// ---------------------------------------------------------------------------
__global__ __launch_bounds__(256) void k3_epi(
    const float* __restrict__ x, const float* __restrict__ nb_part,
    const float* __restrict__ deg_part, const float* __restrict__ Wp,
    const float* __restrict__ bp, const float* __restrict__ gamma,
    const float* __restrict__ beta, float* __restrict__ out) {
  __shared__ float s_nb[16][64];
  __shared__ float s_y[16 * 256];

  const int t    = threadIdx.x;
  const int w    = t >> 6;
  const int lane = t & 63;
  const int row0 = blockIdx.x * 16;

  for (int idx = t; idx < 16 * 64; idx += 256) {
    int r = idx >> 6, c = idx & 63;
    float d = deg_part[row0 + r] + deg_part[NN + row0 + r];
    float s = nb_part[(size_t)(row0 + r) * HH + c] +
              nb_part[(size_t)(NN + row0 + r) * HH + c];
    s_nb[r][c] = (d > 0.5f) ? s / d : 0.f;
  }
  __syncthreads();

  {
    const int f = t;
    float wp[64];
    const float* wrow = Wp + (size_t)f * HH;
#pragma unroll
    for (int j = 0; j < 16; ++j) {
      float4 v = *(const float4*)(wrow + j * 4);
      wp[j * 4 + 0] = v.x; wp[j * 4 + 1] = v.y;
      wp[j * 4 + 2] = v.z; wp[j * 4 + 3] = v.w;
    }
    const float bpf = bp[f];
    for (int r = 0; r < 16; ++r) {
      float a = bpf;
#pragma unroll
      for (int k = 0; k < 64; k += 4) {
        float4 nv = *(const float4*)&s_nb[r][k];
        a += nv.x * wp[k] + nv.y * wp[k + 1] + nv.z * wp[k + 2] + nv.w * wp[k + 3];
      }
      float y = x[(size_t)(row0 + r) * FF + f] + a;
      s_y[r * 256 + f] = y;
    }
  }
  __syncthreads();

  for (int i = 0; i < 4; ++i) {
    const int r = w * 4 + i;
    float4 v = *(const float4*)&s_y[r * 256 + lane * 4];
    float sum = v.x + v.y + v.z + v.w;
    float ss  = v.x * v.x + v.y * v.y + v.z * v.z + v.w * v.w;
#pragma unroll
    for (int o = 32; o >= 1; o >>= 1) {
      sum += __shfl_xor(sum, o, 64);
      ss  += __shfl_xor(ss, o, 64);
    }
    const float mu  = sum * (1.0f / 256.0f);
    const float var = ss * (1.0f / 256.0f) - mu * mu;
    const float rs  = rsqrtf(var + 1e-5f);
    const int f0 = lane * 4;
    float4 g = *(const float4*)(gamma + f0);
    float4 b = *(const float4*)(beta + f0);
    float4 o4;
    o4.x = g.x * (v.x - mu) * rs + b.x;
    o4.y = g.y * (v.y - mu) * rs + b.y;
    o4.z = g.z * (v.z - mu) * rs + b.z;
    o4.w = g.w * (v.w - mu) * rs + b.w;
    *(float4*)(out + (size_t)(row0 + r) * FF + f0) = o4;
  }
}

extern "C" void kernel_launch(void* const* d_in, const int* in_sizes, int n_in,
                              void* d_out, int out_size, void* d_ws, size_t ws_size,
                              hipStream_t stream) {
  const float* x     = (const float*)d_in[0];
  const int*   adj   = (const int*)d_in[1];
  const float* Wt    = (const float*)d_in[2];
  const float* bt    = (const float*)d_in[3];
  // d_in[4] = Wa, d_in[5] = ba: provably dead (softmax scores are row-constant)
  const float* Wp    = (const float*)d_in[6];
  const float* bp    = (const float*)d_in[7];
  const float* gamma = (const float*)d_in[8];
  const float* beta  = (const float*)d_in[9];
  float* out = (float*)d_out;

  // ws layout: hT 1 MB | nb_part 4 MB (two halves) | deg_part 64 KB (float)
  uint16_t* hT       = (uint16_t*)d_ws;
  float*    nb_part  = (float*)((char*)d_ws + (1u << 20));
  float*    deg_part = (float*)((char*)d_ws + (5u << 20));

  k1_h   <<<256,  256, 0, stream>>>(x, Wt, bt, hT);
  k2_attn<<<1024, 256, 0, stream>>>(adj, hT, nb_part, deg_part);
  k3_epi <<<512,  256, 0, stream>>>(x, nb_part, deg_part, Wp, bp, gamma, beta, out);
}

// Round 8
// 441.544 us; speedup vs baseline: 1.0495x; 1.0495x over previous
//
#include <hip/hip_runtime.h>
#include <stdint.h>

#define NN 8192
#define FF 256
#define HH 64

typedef __attribute__((ext_vector_type(8))) short bf16x8;
typedef __attribute__((ext_vector_type(4))) float f32x4;

__device__ __forceinline__ uint16_t f2bf(float f) {
  union { float f; uint32_t i; } c; c.f = f;
  uint32_t r = c.i + 0x7FFFu + ((c.i >> 16) & 1u);
  return (uint16_t)(r >> 16);
}

// ---------------------------------------------------------------------------
// K1: verified r5..r11 GEMM core + verified LDS-transpose tail (passed
// R1/R2/R6/R7). Unchanged. grid = 256 x 32 rows.
// ---------------------------------------------------------------------------
__global__ __launch_bounds__(256) void k1_h(
    const float* __restrict__ x, const float* __restrict__ Wt,
    const float* __restrict__ bt, uint16_t* __restrict__ hT) {
  __shared__ float wtT[256 * 65];
  __shared__ float sbt[64];
  __shared__ uint16_t s_tr[64][34];
  const int t = threadIdx.x;
  const int lane = t & 63;
  const int w = t >> 6;

  for (int i = 0; i < 64; ++i)
    wtT[t * 65 + i] = Wt[(size_t)i * FF + t];
  if (t < 64) sbt[t] = bt[t];
  __syncthreads();

  const int n0 = blockIdx.x * 32;
  const int r0 = n0 + w * 8;
  const float binit = sbt[lane];
  float acc[8];
#pragma unroll
  for (int r = 0; r < 8; ++r) acc[r] = binit;

  for (int f4 = 0; f4 < FF; f4 += 4) {
    float4 xs[8];
#pragma unroll
    for (int r = 0; r < 8; ++r)
      xs[r] = *(const float4*)(x + (size_t)(r0 + r) * FF + f4);
    const float wt0 = wtT[(f4 + 0) * 65 + lane];
    const float wt1 = wtT[(f4 + 1) * 65 + lane];
    const float wt2 = wtT[(f4 + 2) * 65 + lane];
    const float wt3 = wtT[(f4 + 3) * 65 + lane];
#pragma unroll
    for (int r = 0; r < 8; ++r)
      acc[r] += xs[r].x * wt0 + xs[r].y * wt1 + xs[r].z * wt2 + xs[r].w * wt3;
  }

#pragma unroll
  for (int r = 0; r < 8; ++r)
    s_tr[lane][w * 8 + r] = f2bf(acc[r]);
  __syncthreads();
#pragma unroll
  for (int i = 0; i < 4; ++i) {
    int idx = i * 256 + t;
    int c = idx >> 4;
    int d = idx & 15;
    uint32_t v = (uint32_t)s_tr[c][2 * d] | ((uint32_t)s_tr[c][2 * d + 1] << 16);
    *(uint32_t*)(hT + (size_t)c * NN + n0 + 2 * d) = v;
  }
}

// ---------------------------------------------------------------------------
// K2: R6's VERIFIED kernel (passed, best total) with ONE change: T14
// issue-early/write-late staging split. Tile t+1's global loads are issued
// right after the stage->compute barrier, so their ~900cy latency hides
// under tile t's compute + barrier + convert instead of sitting on the
// critical path. Same maps, same 2 barriers/tile, ordering by plain
// __syncthreads ONLY (no asm fences). __launch_bounds__(256,4) pins
// VGPR <= 128 so 4 blocks/CU survives the +32 VGPR of p[8].
// DMA mechanism of R7 reverted (regressed ~25us).
// ---------------------------------------------------------------------------
__global__ __launch_bounds__(256, 4) void k2_attn(
    const int* __restrict__ adj, const uint16_t* __restrict__ hT,
    float* __restrict__ nb_part, float* __restrict__ deg_part) {
  __shared__ __align__(16) unsigned char af[16 * 1024];  // 16 rows x 1 KB
  __shared__ float s_part[4][16][64];                    // 16 KB
  __shared__ float s_degw[4][16];

  const int t    = threadIdx.x;
  const int w    = t >> 6;
  const int lane = t & 63;
  const int m    = lane & 15;
  const int q    = lane >> 4;
  const int g    = blockIdx.x >> 1;
  const int half = blockIdx.x & 1;
  const int row0 = g * 16;
  const int rsw  = (m & 7) << 4;

  bf16x8 vone;
#pragma unroll
  for (int j = 0; j < 8; ++j) vone[j] = (short)0x3F80;

  f32x4 acc0 = 0, acc1 = 0, acc2 = 0, acc3 = 0, accd = 0;
  const uint16_t* __restrict__ hrow = hT + (size_t)m * NN;
  const int sr = t >> 7;      // 0/1: which row of the pair this thread stages
  const int sc = t & 127;     // int4 group within the 512-col row
  const int base = half * (NN / 2);

#define STAGE_LOAD(P, C0)                                                    \
  _Pragma("unroll") for (int j = 0; j < 8; ++j)                              \
    P[j] = *(const int4*)(adj + (size_t)(row0 + 2 * j + sr) * NN +           \
                          (C0) + sc * 4);

#define STAGE_WRITE(P)                                                       \
  _Pragma("unroll") for (int j = 0; j < 8; ++j) {                            \
    const int r_ = 2 * j + sr;                                               \
    uint32_t lo_ = ((uint32_t)P[j].x | ((uint32_t)P[j].y << 16)) * 0x3F80u;  \
    uint32_t hi_ = ((uint32_t)P[j].z | ((uint32_t)P[j].w << 16)) * 0x3F80u;  \
    uint2 w2_; w2_.x = lo_; w2_.y = hi_;                                     \
    *(uint2*)(af + r_ * 1024 + (((uint32_t)(sc * 8)) ^ ((r_ & 7) << 4))) = w2_; \
  }

  int4 p[8];
  STAGE_LOAD(p, base)                      // prologue: tile 0 into regs

  for (int tile = 0; tile < 8; ++tile) {
    const int c0 = base + tile * 512;
    STAGE_WRITE(p)                         // convert + ds_write current tile
    __syncthreads();                       // af ready for all waves
    if (tile < 7) STAGE_LOAD(p, c0 + 512)  // issue next tile EARLY (T14)

    // ---- compute from af (R6 verbatim body) ----
#pragma unroll
    for (int it = 0; it < 2; ++it) {
      const int kl = w * 128 + it * 64;
      const int k0 = c0 + kl + q * 8;
      const int k1 = k0 + 32;
      bf16x8 afA = *(const bf16x8*)(af + m * 1024 +
                                    (((uint32_t)((kl + q * 8) * 2)) ^ rsw));
      bf16x8 afB = *(const bf16x8*)(af + m * 1024 +
                                    (((uint32_t)((kl + q * 8) * 2 + 64)) ^ rsw));
      bf16x8 b0 = *(const bf16x8*)(hrow + k0);
      bf16x8 b1 = *(const bf16x8*)(hrow + 16 * NN + k0);
      bf16x8 b2 = *(const bf16x8*)(hrow + 32 * NN + k0);
      bf16x8 b3 = *(const bf16x8*)(hrow + 48 * NN + k0);
      bf16x8 d0 = *(const bf16x8*)(hrow + k1);
      bf16x8 d1 = *(const bf16x8*)(hrow + 16 * NN + k1);
      bf16x8 d2 = *(const bf16x8*)(hrow + 32 * NN + k1);
      bf16x8 d3 = *(const bf16x8*)(hrow + 48 * NN + k1);
      acc0 = __builtin_amdgcn_mfma_f32_16x16x32_bf16(afA, b0, acc0, 0, 0, 0);
      acc1 = __builtin_amdgcn_mfma_f32_16x16x32_bf16(afA, b1, acc1, 0, 0, 0);
      acc2 = __builtin_amdgcn_mfma_f32_16x16x32_bf16(afA, b2, acc2, 0, 0, 0);
      acc3 = __builtin_amdgcn_mfma_f32_16x16x32_bf16(afA, b3, acc3, 0, 0, 0);
      accd = __builtin_amdgcn_mfma_f32_16x16x32_bf16(afA, vone, accd, 0, 0, 0);
      acc0 = __builtin_amdgcn_mfma_f32_16x16x32_bf16(afB, d0, acc0, 0, 0, 0);
      acc1 = __builtin_amdgcn_mfma_f32_16x16x32_bf16(afB, d1, acc1, 0, 0, 0);
      acc2 = __builtin_amdgcn_mfma_f32_16x16x32_bf16(afB, d2, acc2, 0, 0, 0);
      acc3 = __builtin_amdgcn_mfma_f32_16x16x32_bf16(afB, d3, acc3, 0, 0, 0);
      accd = __builtin_amdgcn_mfma_f32_16x16x32_bf16(afB, vone, accd, 0, 0, 0);
    }
    __syncthreads();                       // compute done before next WRITE
  }
#undef STAGE_LOAD
#undef STAGE_WRITE

  // ---- acc -> s_part (verified verbatim map) + deg-via-MFMA (verbatim) ----
#pragma unroll
  for (int rg = 0; rg < 4; ++rg) {
    s_part[w][q * 4 + rg][ 0 + m] = acc0[rg];
    s_part[w][q * 4 + rg][16 + m] = acc1[rg];
    s_part[w][q * 4 + rg][32 + m] = acc2[rg];
    s_part[w][q * 4 + rg][48 + m] = acc3[rg];
  }
  if (m == 0) {
#pragma unroll
    for (int rg = 0; rg < 4; ++rg) s_degw[w][q * 4 + rg] = accd[rg];
  }
  __syncthreads();

  // ---- cross-wave reduce -> this half's disjoint partial buffers ----
  float* __restrict__ dst = nb_part + ((size_t)half * NN + row0) * HH;
  for (int idx = t; idx < 16 * 64; idx += 256) {
    int r = idx >> 6, c = idx & 63;
    float s = s_part[0][r][c] + s_part[1][r][c] +
              s_part[2][r][c] + s_part[3][r][c];
    dst[(size_t)r * HH + c] = s;
  }
  if (t < 16) {
    float d = s_degw[0][t] + s_degw[1][t] + s_degw[2][t] + s_degw[3][t];
    deg_part[half * NN + row0 + t] = d;
  }
}

// ---------------------------------------------------------------------------
// K3: epilogue, verified maps (passed R6/R7). Unchanged.
// ---------------------------------------------------------------------------
__global__ __launch_bounds__(256) void k3_epi(
    const float* __restrict__ x, const float* __restrict__ nb_part,
    const float* __restrict__ deg_part, const float* __restrict__ Wp,
    const float* __restrict__ bp, const float* __restrict__ gamma,
    const float* __restrict__ beta, float* __restrict__ out) {
  __shared__ float s_nb[16][64];
  __shared__ float s_y[16 * 256];

  const int t    = threadIdx.x;
  const int w    = t >> 6;
  const int lane = t & 63;
  const int row0 = blockIdx.x * 16;

  for (int idx = t; idx < 16 * 64; idx += 256) {
    int r = idx >> 6, c = idx & 63;
    float d = deg_part[row0 + r] + deg_part[NN + row0 + r];
    float s = nb_part[(size_t)(row0 + r) * HH + c] +
              nb_part[(size_t)(NN + row0 + r) * HH + c];
    s_nb[r][c] = (d > 0.5f) ? s / d : 0.f;
  }
  __syncthreads();

  {
    const int f = t;
    float wp[64];
    const float* wrow = Wp + (size_t)f * HH;
#pragma unroll
    for (int j = 0; j < 16; ++j) {
      float4 v = *(const float4*)(wrow + j * 4);
      wp[j * 4 + 0] = v.x; wp[j * 4 + 1] = v.y;
      wp[j * 4 + 2] = v.z; wp[j * 4 + 3] = v.w;
    }
    const float bpf = bp[f];
    for (int r = 0; r < 16; ++r) {
      float a = bpf;
#pragma unroll
      for (int k = 0; k < 64; k += 4) {
        float4 nv = *(const float4*)&s_nb[r][k];
        a += nv.x * wp[k] + nv.y * wp[k + 1] + nv.z * wp[k + 2] + nv.w * wp[k + 3];
      }
      float y = x[(size_t)(row0 + r) * FF + f] + a;
      s_y[r * 256 + f] = y;
    }
  }
  __syncthreads();

  for (int i = 0; i < 4; ++i) {
    const int r = w * 4 + i;
    float4 v = *(const float4*)&s_y[r * 256 + lane * 4];
    float sum = v.x + v.y + v.z + v.w;
    float ss  = v.x * v.x + v.y * v.y + v.z * v.z + v.w * v.w;
#pragma unroll
    for (int o = 32; o >= 1; o >>= 1) {
      sum += __shfl_xor(sum, o, 64);
      ss  += __shfl_xor(ss, o, 64);
    }
    const float mu  = sum * (1.0f / 256.0f);
    const float var = ss * (1.0f / 256.0f) - mu * mu;
    const float rs  = rsqrtf(var + 1e-5f);
    const int f0 = lane * 4;
    float4 g = *(const float4*)(gamma + f0);
    float4 b = *(const float4*)(beta + f0);
    float4 o4;
    o4.x = g.x * (v.x - mu) * rs + b.x;
    o4.y = g.y * (v.y - mu) * rs + b.y;
    o4.z = g.z * (v.z - mu) * rs + b.z;
    o4.w = g.w * (v.w - mu) * rs + b.w;
    *(float4*)(out + (size_t)(row0 + r) * FF + f0) = o4;
  }
}

extern "C" void kernel_launch(void* const* d_in, const int* in_sizes, int n_in,
                              void* d_out, int out_size, void* d_ws, size_t ws_size,
                              hipStream_t stream) {
  const float* x     = (const float*)d_in[0];
  const int*   adj   = (const int*)d_in[1];
  const float* Wt    = (const float*)d_in[2];
  const float* bt    = (const float*)d_in[3];
  // d_in[4] = Wa, d_in[5] = ba: provably dead (softmax scores are row-constant)
  const float* Wp    = (const float*)d_in[6];
  const float* bp    = (const float*)d_in[7];
  const float* gamma = (const float*)d_in[8];
  const float* beta  = (const float*)d_in[9];
  float* out = (float*)d_out;

  // ws layout: hT 1 MB | nb_part 4 MB (two halves) | deg_part 64 KB (float)
  uint16_t* hT       = (uint16_t*)d_ws;
  float*    nb_part  = (float*)((char*)d_ws + (1u << 20));
  float*    deg_part = (float*)((char*)d_ws + (5u << 20));

  k1_h   <<<256,  256, 0, stream>>>(x, Wt, bt, hT);
  k2_attn<<<1024, 256, 0, stream>>>(adj, hT, nb_part, deg_part);
  k3_epi <<<512,  256, 0, stream>>>(x, nb_part, deg_part, Wp, bp, gamma, beta, out);
}